// Round 4
// baseline (484.688 us; speedup 1.0000x reference)
//
#include <hip/hip_runtime.h>
#include <cstddef>

typedef __attribute__((ext_vector_type(8))) short s16x8;
typedef __attribute__((ext_vector_type(4))) float f32x4;
typedef __attribute__((ext_vector_type(4))) unsigned short us4;

static __device__ __forceinline__ float bf2f(unsigned short u) {
    union { unsigned u; float f; } v;
    v.u = ((unsigned)u) << 16;
    return v.f;
}

static __device__ __forceinline__ unsigned short f2bf(float f) {
    union { float f; unsigned u; } v;
    v.f = f;
    unsigned r = v.u + 0x7fffu + ((v.u >> 16) & 1u);  // RNE
    return (unsigned short)(r >> 16);
}

// single-op bf16 convert via HW pack instruction (RNE on gfx950)
static __device__ __forceinline__ unsigned short f2bf_fast(float f) {
    unsigned r;
    asm("v_cvt_pk_bf16_f32 %0, %1, %2" : "=v"(r) : "v"(f), "v"(f));
    return (unsigned short)r;
}

#if __has_builtin(__builtin_amdgcn_exp2f)
#define EXP2F(x) __builtin_amdgcn_exp2f(x)
#else
#define EXP2F(x) exp2f(x)
#endif

// dtype-generic scalar load -> float
static __device__ __forceinline__ float ldf(const unsigned short* p, size_t i) { return bf2f(p[i]); }
static __device__ __forceinline__ float ldf(const float* p, size_t i) { return p[i]; }
// dtype-generic store from float
static __device__ __forceinline__ void stf(unsigned short* p, size_t i, float v) { p[i] = f2bf(v); }
static __device__ __forceinline__ void stf(float* p, size_t i, float v) { p[i] = v; }

// ---------------------------------------------------------------------------
// dtype probe: flags[0]: 0 = bf16 inputs, 1 = fp32. flags[1] zeroed here.
// ---------------------------------------------------------------------------
__global__ __launch_bounds__(256) void probe_dtype(
    const unsigned short* __restrict__ q, unsigned* __restrict__ flags)
{
    __shared__ float red[256];
    const int t = threadIdx.x;
    float m = 0.0f;
    for (int i = t; i < 16384; i += 256) {
        float x = fabsf(bf2f(q[i]));
        if (!(x == x)) x = 1.0e30f;
        m = fmaxf(m, x);
    }
    red[t] = m;
    __syncthreads();
    for (int s = 128; s > 0; s >>= 1) {
        if (t < s) red[t] = fmaxf(red[t], red[t + s]);
        __syncthreads();
    }
    if (t == 0) {
        flags[0] = (red[0] < 1000.0f) ? 0u : 1u;
        flags[1] = 0u;
    }
}

// ---------------------------------------------------------------------------
// att_mask all-zero probe (bitwise). flags[1]=1 iff any nonzero.
// ---------------------------------------------------------------------------
__global__ __launch_bounds__(256) void probe_zero(
    const uint4* __restrict__ m, unsigned* __restrict__ flags)
{
    const unsigned dt = flags[0];
    const size_t n = dt ? 2097152u : 1048576u;
    unsigned acc = 0;
    for (size_t i = (size_t)blockIdx.x * 256 + threadIdx.x; i < n;
         i += (size_t)gridDim.x * 256) {
        uint4 v = m[i];
        acc |= v.x | v.y | v.z | v.w;
    }
    if (acc) atomicOr(&flags[1], 1u);
}

// ---------------------------------------------------------------------------
// fused 3-tensor fp32->bf16 convert (runs iff flags[0]==1); blockIdx.y picks
// ---------------------------------------------------------------------------
__global__ __launch_bounds__(256) void cvt3_f32_bf16(
    const float4* __restrict__ s0, us4* __restrict__ d0,
    const float4* __restrict__ s1, us4* __restrict__ d1,
    const float4* __restrict__ s2, us4* __restrict__ d2,
    unsigned n4, const unsigned* __restrict__ flags)
{
    if (flags[0] != 1u) return;
    const float4* s = (blockIdx.y == 0) ? s0 : (blockIdx.y == 1) ? s1 : s2;
    us4* d = (blockIdx.y == 0) ? d0 : (blockIdx.y == 1) ? d1 : d2;
    for (unsigned i = blockIdx.x * 256u + threadIdx.x; i < n4;
         i += gridDim.x * 256u) {
        float4 v = s[i];
        us4 o;
        o.x = f2bf(v.x); o.y = f2bf(v.y); o.z = f2bf(v.z); o.w = f2bf(v.w);
        d[i] = o;
    }
}

// fused 3-tensor bf16 copy (runs iff flags[0]==0)
__global__ __launch_bounds__(256) void copy3_bf16(
    const uint4* __restrict__ s0, uint4* __restrict__ d0,
    const uint4* __restrict__ s1, uint4* __restrict__ d1,
    const uint4* __restrict__ s2, uint4* __restrict__ d2,
    unsigned n16, const unsigned* __restrict__ flags)
{
    if (flags[0] != 0u) return;
    const uint4* s = (blockIdx.y == 0) ? s0 : (blockIdx.y == 1) ? s1 : s2;
    uint4* d = (blockIdx.y == 0) ? d0 : (blockIdx.y == 1) ? d1 : d2;
    for (unsigned i = blockIdx.x * 256u + threadIdx.x; i < n16;
         i += gridDim.x * 256u)
        d[i] = s[i];
}

// single-tensor fp32->bf16 (for seq_mask; fp32 path only)
__global__ __launch_bounds__(256) void cvt_f32_bf16(
    const float4* __restrict__ src, us4* __restrict__ dst, unsigned n4,
    const unsigned* __restrict__ flags)
{
    if (flags[0] != 1u) return;
    for (unsigned i = blockIdx.x * 256u + threadIdx.x; i < n4;
         i += gridDim.x * 256u) {
        float4 v = src[i];
        us4 o;
        o.x = f2bf(v.x); o.y = f2bf(v.y); o.z = f2bf(v.z); o.w = f2bf(v.w);
        dst[i] = o;
    }
}

// ---------------------------------------------------------------------------
// Weight transpose to bf16: dst[n][k] = (bf16)src[k][n], 1024x1024
// ---------------------------------------------------------------------------
template <typename T>
__global__ __launch_bounds__(256) void transpose_w(
    const T* __restrict__ src, unsigned short* __restrict__ dst,
    const unsigned* __restrict__ flag, unsigned want)
{
    if (*flag != want) return;
    __shared__ unsigned short tile[32][33];
    const int c0 = blockIdx.x * 32, r0 = blockIdx.y * 32;
    const int tx = threadIdx.x, ty = threadIdx.y;  // block (32,8)
#pragma unroll
    for (int i = 0; i < 32; i += 8)
        tile[ty + i][tx] = f2bf(ldf(src, (size_t)(r0 + ty + i) * 1024 + c0 + tx));
    __syncthreads();
#pragma unroll
    for (int i = 0; i < 32; i += 8)
        dst[(size_t)(c0 + ty + i) * 1024 + r0 + tx] = tile[tx][ty + i];
}

// fused 3-weight transpose; blockIdx.z picks tensor
template <typename T>
__global__ __launch_bounds__(256) void transpose_w3(
    const T* __restrict__ s0, const T* __restrict__ s1, const T* __restrict__ s2,
    unsigned short* __restrict__ d0, unsigned short* __restrict__ d1,
    unsigned short* __restrict__ d2,
    const unsigned* __restrict__ flag, unsigned want)
{
    if (*flag != want) return;
    const T* src = (blockIdx.z == 0) ? s0 : (blockIdx.z == 1) ? s1 : s2;
    unsigned short* dst = (blockIdx.z == 0) ? d0 : (blockIdx.z == 1) ? d1 : d2;
    __shared__ unsigned short tile[32][33];
    const int c0 = blockIdx.x * 32, r0 = blockIdx.y * 32;
    const int tx = threadIdx.x, ty = threadIdx.y;  // block (32,8)
#pragma unroll
    for (int i = 0; i < 32; i += 8)
        tile[ty + i][tx] = f2bf(ldf(src, (size_t)(r0 + ty + i) * 1024 + c0 + tx));
    __syncthreads();
#pragma unroll
    for (int i = 0; i < 32; i += 8)
        dst[(size_t)(c0 + ty + i) * 1024 + r0 + tx] = tile[tx][ty + i];
}

// ---------------------------------------------------------------------------
// GEMM: C[M=4096,N=1024] = A[4096,1024] @ Bt[1024,1024]^T  (A always bf16)
// want==2 -> always run; else gated on flags[0]==want (output dtype).
// mode 0: row-major store; 1: head-split; 2: transposed head-split (V)
// ---------------------------------------------------------------------------
template <typename TO>
__global__ __launch_bounds__(256) void gemm_kernel(
    const unsigned short* __restrict__ A, const unsigned short* __restrict__ Bt,
    TO* __restrict__ out, int mode, const unsigned* __restrict__ flags, unsigned want)
{
    if (want != 2u && flags[0] != want) return;
    const int K = 1024;
    __shared__ __align__(16) unsigned short lA[64 * 72];
    __shared__ __align__(16) unsigned short lB[64 * 72];

    const int m0 = blockIdx.y * 64, n0 = blockIdx.x * 64;
    const int t = threadIdx.x;
    const int w = t >> 6, l = t & 63, quad = l >> 4, l15 = l & 15;
    const int srow = t >> 2, scol = (t & 3) * 16;

    f32x4 acc[4] = {};

    for (int k0 = 0; k0 < K; k0 += 64) {
        const uint4* ga = (const uint4*)(A + (size_t)(m0 + srow) * K + k0 + scol);
        uint4 a0 = ga[0], a1 = ga[1];
        const uint4* gb = (const uint4*)(Bt + (size_t)(n0 + srow) * K + k0 + scol);
        uint4 b0 = gb[0], b1 = gb[1];
        *(uint4*)&lA[srow * 72 + scol] = a0;
        *(uint4*)&lA[srow * 72 + scol + 8] = a1;
        *(uint4*)&lB[srow * 72 + scol] = b0;
        *(uint4*)&lB[srow * 72 + scol + 8] = b1;
        __syncthreads();
#pragma unroll
        for (int kk = 0; kk < 64; kk += 32) {
            s16x8 af = *(const s16x8*)&lA[(w * 16 + l15) * 72 + kk + quad * 8];
#pragma unroll
            for (int g = 0; g < 4; g++) {
                s16x8 bf = *(const s16x8*)&lB[(g * 16 + l15) * 72 + kk + quad * 8];
                acc[g] = __builtin_amdgcn_mfma_f32_16x16x32_bf16(af, bf, acc[g], 0, 0, 0);
            }
        }
        __syncthreads();
    }

#pragma unroll
    for (int g = 0; g < 4; g++) {
#pragma unroll
        for (int r = 0; r < 4; r++) {
            int row = m0 + w * 16 + quad * 4 + r;
            int col = n0 + g * 16 + l15;
            float val = acc[g][r];
            if (mode == 0) {
                stf(out, (size_t)row * 1024 + col, val);
            } else {
                int b = row >> 11, s = row & 2047;
                int h = col >> 6, d = col & 63;
                if (mode == 1)
                    stf(out, (((size_t)(b * 16 + h) * 2048) + s) * 64 + d, val);
                else
                    stf(out, (((size_t)(b * 16 + h) * 64) + d) * 2048 + s, val);
            }
        }
    }
}

// ---------------------------------------------------------------------------
// Flash attention, post-softmax multiplicative seq_mask (bf16 smask always).
// VALU-lean softmax: exp2 domain, deferred l-reduction, exact defer-rescale,
// cvt_pk bf16 stores, XOR-swizzled lP to kill P-write bank conflicts.
// ---------------------------------------------------------------------------
template <typename TM>
__global__ __launch_bounds__(256) void attn_kernel(
    const unsigned short* __restrict__ qh, const unsigned short* __restrict__ kh,
    const unsigned short* __restrict__ vt, const TM* __restrict__ amask,
    const unsigned short* __restrict__ smask, unsigned short* __restrict__ aout,
    const unsigned* __restrict__ flags, unsigned want)
{
    if (flags[0] != want) return;
    const bool useA = (flags[1] != 0u);
    const int S = 2048, DK = 64, H = 16;
    const int qt = blockIdx.x, h = blockIdx.y, b = blockIdx.z;
    const unsigned short* qhb = qh + (size_t)(b * H + h) * S * DK;
    const unsigned short* khb = kh + (size_t)(b * H + h) * S * DK;
    const unsigned short* vtb = vt + (size_t)(b * H + h) * DK * S;

    __shared__ __align__(16) unsigned short lK[64 * 72];
    __shared__ __align__(16) unsigned short lV[64 * 72];
    __shared__ __align__(16) unsigned short lP[4][16 * 72];

    const int t = threadIdx.x;
    const int w = t >> 6, l = t & 63, quad = l >> 4, l15 = l & 15;
    const int q0 = qt * 64;
    const int srow = t >> 2, scol = (t & 3) * 16;

    const float SCALE2 = 0.18033688011112042f;  // 0.125 * log2(e)
    const float LOG2E  = 1.4426950408889634f;

    // hoisted per-row mask pointers (fully unrolled -> static indexing)
    const unsigned short* mr[4];
    const TM* ar[4];
#pragma unroll
    for (int r = 0; r < 4; r++) {
        const size_t rowoff = (size_t)(q0 + w * 16 + quad * 4 + r) * S + l15;
        mr[r] = smask + (size_t)b * S * S + rowoff;
        ar[r] = amask + (size_t)b * S * S + rowoff;
    }

    const int qrow_a = q0 + w * 16 + l15;
    s16x8 qf0 = *(const s16x8*)&qhb[(size_t)qrow_a * DK + quad * 8];
    s16x8 qf1 = *(const s16x8*)&qhb[(size_t)qrow_a * DK + 32 + quad * 8];

    float mrun[4], lsum[4];
    f32x4 o[4] = {};
#pragma unroll
    for (int r = 0; r < 4; r++) { mrun[r] = -INFINITY; lsum[r] = 0.0f; }

    for (int k0 = 0; k0 < S; k0 += 64) {
        const uint4* gk = (const uint4*)&khb[(size_t)(k0 + srow) * DK + scol];
        const uint4* gv = (const uint4*)&vtb[(size_t)srow * S + k0 + scol];
        uint4 ka = gk[0], kb = gk[1];
        uint4 va = gv[0], vb = gv[1];
        *(uint4*)&lK[srow * 72 + scol] = ka;
        *(uint4*)&lK[srow * 72 + scol + 8] = kb;
        *(uint4*)&lV[srow * 72 + scol] = va;
        *(uint4*)&lV[srow * 72 + scol + 8] = vb;
        __syncthreads();

        f32x4 sc[4] = {};
#pragma unroll
        for (int kk = 0; kk < 64; kk += 32) {
            s16x8 af = (kk == 0) ? qf0 : qf1;
#pragma unroll
            for (int g = 0; g < 4; g++) {
                s16x8 bf = *(const s16x8*)&lK[(g * 16 + l15) * 72 + kk + quad * 8];
                sc[g] = __builtin_amdgcn_mfma_f32_16x16x32_bf16(af, bf, sc[g], 0, 0, 0);
            }
        }

#pragma unroll
        for (int r = 0; r < 4; r++) {
            float sv[4];
            if (useA) {
#pragma unroll
                for (int g = 0; g < 4; g++)
                    sv[g] = fmaf((float)ldf(ar[r], k0 + g * 16), LOG2E,
                                 sc[g][r] * SCALE2);
            } else {
#pragma unroll
                for (int g = 0; g < 4; g++) sv[g] = sc[g][r] * SCALE2;
            }
            float mx = fmaxf(fmaxf(sv[0], sv[1]), fmaxf(sv[2], sv[3]));
#pragma unroll
            for (int d = 1; d < 16; d <<= 1) mx = fmaxf(mx, __shfl_xor(mx, d));

            if (!__all(mx <= mrun[r])) {
                float mnew = fmaxf(mrun[r], mx);
                float alpha = EXP2F(mrun[r] - mnew);  // exp2(-inf)=0 on 1st tile
                lsum[r] *= alpha;
#pragma unroll
                for (int g = 0; g < 4; g++) o[g][r] *= alpha;
                mrun[r] = mnew;
            }

            const int rowp = quad * 4 + r;
            const int rsw = (rowp & 8) << 1;  // lP XOR swizzle
            float e0 = EXP2F(sv[0] - mrun[r]);
            float e1 = EXP2F(sv[1] - mrun[r]);
            float e2 = EXP2F(sv[2] - mrun[r]);
            float e3 = EXP2F(sv[3] - mrun[r]);
            lsum[r] += (e0 + e1) + (e2 + e3);
            lP[w][rowp * 72 + ((0 * 16 + l15) ^ rsw)] = f2bf_fast(e0 * bf2f(mr[r][k0 + 0]));
            lP[w][rowp * 72 + ((1 * 16 + l15) ^ rsw)] = f2bf_fast(e1 * bf2f(mr[r][k0 + 16]));
            lP[w][rowp * 72 + ((2 * 16 + l15) ^ rsw)] = f2bf_fast(e2 * bf2f(mr[r][k0 + 32]));
            lP[w][rowp * 72 + ((3 * 16 + l15) ^ rsw)] = f2bf_fast(e3 * bf2f(mr[r][k0 + 48]));
        }
        __syncthreads();

        const int rdsw = (l15 & 8) << 1;  // read-side un-swizzle (row = l15)
#pragma unroll
        for (int kk = 0; kk < 64; kk += 32) {
            s16x8 pf = *(const s16x8*)&lP[w][l15 * 72 + ((kk + quad * 8) ^ rdsw)];
#pragma unroll
            for (int g = 0; g < 4; g++) {
                s16x8 vf = *(const s16x8*)&lV[(g * 16 + l15) * 72 + kk + quad * 8];
                o[g] = __builtin_amdgcn_mfma_f32_16x16x32_bf16(pf, vf, o[g], 0, 0, 0);
            }
        }
        __syncthreads();
    }

#pragma unroll
    for (int r = 0; r < 4; r++) {
        float ls = lsum[r];
#pragma unroll
        for (int d = 1; d < 16; d <<= 1) ls += __shfl_xor(ls, d);
        float inv = 1.0f / ls;
        const int qr = q0 + w * 16 + quad * 4 + r;
#pragma unroll
        for (int g = 0; g < 4; g++) {
            aout[((size_t)(b * S + qr)) * 1024 + h * 64 + g * 16 + l15] =
                f2bf_fast(o[g][r] * inv);
        }
    }
}

// ---------------------------------------------------------------------------
extern "C" void kernel_launch(void* const* d_in, const int* in_sizes, int n_in,
                              void* d_out, int out_size, void* d_ws, size_t ws_size,
                              hipStream_t stream)
{
    // setup_inputs order: q, v, k, att_mask, seq_mask, Wq, Wk, Wv, Wo
    const void* q   = d_in[0];
    const void* v   = d_in[1];
    const void* k   = d_in[2];
    const void* att = d_in[3];
    const void* seq = d_in[4];
    const void* Wq  = d_in[5];
    const void* Wk  = d_in[6];
    const void* Wv  = d_in[7];
    const void* Wo  = d_in[8];

    const size_t WELEM = 1024 * 1024;
    const size_t HELEM = (size_t)2 * 16 * 2048 * 64;  // 4,194,304 elements

    unsigned* flags = (unsigned*)d_ws;
    unsigned short* base = (unsigned short*)((char*)d_ws + 512);
    unsigned short* r0 = base;           // 8MB: Wq^T,Wk^T,Wv^T ; later ao
    unsigned short* qh = base + HELEM;   // 8MB: qh ; later Wo^T
    unsigned short* kh = qh + HELEM;     // 8MB
    unsigned short* vt = kh + HELEM;     // 8MB
    unsigned short* qb = vt + HELEM;     // 8MB bf16(q)
    unsigned short* kb = qb + HELEM;     // 8MB bf16(k)
    unsigned short* vb = kb + HELEM;     // 8MB bf16(v)
    unsigned short* seqb = qb;           // 16MB bf16(seq_mask), overlaps qb+kb
                                         //  (written AFTER projections finish)
    // total ws: 512 + 7*8MB = 56.5 MB

    const dim3 tg(32, 32), tb(32, 8);
    const dim3 tg3(32, 32, 3);
    const dim3 gg(16, 64), gb(256);
    const dim3 ag(32, 16, 2), ab(256);

    probe_dtype<<<1, 256, 0, stream>>>((const unsigned short*)q, flags);
    probe_zero<<<1024, 256, 0, stream>>>((const uint4*)att, flags);

    // ---- bulk convert/copy q,k,v to bf16 (one of the pair no-ops) ----
    const unsigned n4h = 1048576u, n16h = 524288u;   // HELEM/4, HELEM/8
    cvt3_f32_bf16<<<dim3(512, 3), 256, 0, stream>>>(
        (const float4*)q, (us4*)qb, (const float4*)k, (us4*)kb,
        (const float4*)v, (us4*)vb, n4h, flags);
    copy3_bf16<<<dim3(512, 3), 256, 0, stream>>>(
        (const uint4*)q, (uint4*)qb, (const uint4*)k, (uint4*)kb,
        (const uint4*)v, (uint4*)vb, n16h, flags);

    // ---- transposes of Wq, Wk, Wv (one dtype variant no-ops) ----
    transpose_w3<unsigned short><<<tg3, tb, 0, stream>>>(
        (const unsigned short*)Wq, (const unsigned short*)Wk, (const unsigned short*)Wv,
        r0 + 0 * WELEM, r0 + 1 * WELEM, r0 + 2 * WELEM, flags, 0);
    transpose_w3<float><<<tg3, tb, 0, stream>>>(
        (const float*)Wq, (const float*)Wk, (const float*)Wv,
        r0 + 0 * WELEM, r0 + 1 * WELEM, r0 + 2 * WELEM, flags, 1);

    // ---- projections (always run; A is bf16) ----
    gemm_kernel<unsigned short><<<gg, gb, 0, stream>>>(qb, r0 + 0 * WELEM, qh, 1, flags, 2);
    gemm_kernel<unsigned short><<<gg, gb, 0, stream>>>(kb, r0 + 1 * WELEM, kh, 1, flags, 2);
    gemm_kernel<unsigned short><<<gg, gb, 0, stream>>>(vb, r0 + 2 * WELEM, vt, 2, flags, 2);

    // ---- seq_mask -> bf16 (fp32 path only; bf16 path reads seq directly) ----
    const unsigned n4s = 2097152u;  // 8,388,608 elems / 4
    cvt_f32_bf16<<<2048, 256, 0, stream>>>((const float4*)seq, (us4*)seqb, n4s, flags);

    // ---- attention (ao overwrites r0; weights no longer needed) ----
    unsigned short* ao = r0;
    attn_kernel<unsigned short><<<ag, ab, 0, stream>>>(
        qh, kh, vt, (const unsigned short*)att, (const unsigned short*)seq, ao, flags, 0);
    attn_kernel<float><<<ag, ab, 0, stream>>>(
        qh, kh, vt, (const float*)att, seqb, ao, flags, 1);

    // ---- Wo transpose into qh region (qh no longer needed) ----
    transpose_w<unsigned short><<<tg, tb, 0, stream>>>((const unsigned short*)Wo, qh, flags, 0);
    transpose_w<float><<<tg, tb, 0, stream>>>((const float*)Wo, qh, flags, 1);

    // ---- output projection ----
    gemm_kernel<unsigned short><<<gg, gb, 0, stream>>>(ao, qh, (unsigned short*)d_out, 0, flags, 0);
    gemm_kernel<float><<<gg, gb, 0, stream>>>(ao, qh, (float*)d_out, 0, flags, 1);
}

// Round 5
// 407.837 us; speedup vs baseline: 1.1884x; 1.1884x over previous
//
#include <hip/hip_runtime.h>
#include <cstddef>

typedef __attribute__((ext_vector_type(8))) short s16x8;
typedef __attribute__((ext_vector_type(4))) float f32x4;
typedef __attribute__((ext_vector_type(4))) unsigned short us4;

static __device__ __forceinline__ float bf2f(unsigned short u) {
    union { unsigned u; float f; } v;
    v.u = ((unsigned)u) << 16;
    return v.f;
}

static __device__ __forceinline__ unsigned short f2bf(float f) {
    union { float f; unsigned u; } v;
    v.f = f;
    unsigned r = v.u + 0x7fffu + ((v.u >> 16) & 1u);  // RNE
    return (unsigned short)(r >> 16);
}

// single-op bf16 convert via HW pack instruction (RNE on gfx950)
static __device__ __forceinline__ unsigned short f2bf_fast(float f) {
    unsigned r;
    asm("v_cvt_pk_bf16_f32 %0, %1, %2" : "=v"(r) : "v"(f), "v"(f));
    return (unsigned short)r;
}

#if __has_builtin(__builtin_amdgcn_exp2f)
#define EXP2F(x) __builtin_amdgcn_exp2f(x)
#else
#define EXP2F(x) exp2f(x)
#endif

// dtype-generic scalar load -> float
static __device__ __forceinline__ float ldf(const unsigned short* p, size_t i) { return bf2f(p[i]); }
static __device__ __forceinline__ float ldf(const float* p, size_t i) { return p[i]; }
// dtype-generic store from float
static __device__ __forceinline__ void stf(unsigned short* p, size_t i, float v) { p[i] = f2bf(v); }
static __device__ __forceinline__ void stf(float* p, size_t i, float v) { p[i] = v; }

// ---------------------------------------------------------------------------
// dtype probe: flags[0]: 0 = bf16 inputs, 1 = fp32. flags[1] zeroed here.
// ---------------------------------------------------------------------------
__global__ __launch_bounds__(256) void probe_dtype(
    const unsigned short* __restrict__ q, unsigned* __restrict__ flags)
{
    __shared__ float red[256];
    const int t = threadIdx.x;
    float m = 0.0f;
    for (int i = t; i < 16384; i += 256) {
        float x = fabsf(bf2f(q[i]));
        if (!(x == x)) x = 1.0e30f;
        m = fmaxf(m, x);
    }
    red[t] = m;
    __syncthreads();
    for (int s = 128; s > 0; s >>= 1) {
        if (t < s) red[t] = fmaxf(red[t], red[t + s]);
        __syncthreads();
    }
    if (t == 0) {
        flags[0] = (red[0] < 1000.0f) ? 0u : 1u;
        flags[1] = 0u;
    }
}

// ---------------------------------------------------------------------------
// att_mask all-zero probe (bitwise). flags[1]=1 iff any nonzero.
// ---------------------------------------------------------------------------
__global__ __launch_bounds__(256) void probe_zero(
    const uint4* __restrict__ m, unsigned* __restrict__ flags)
{
    const unsigned dt = flags[0];
    const size_t n = dt ? 2097152u : 1048576u;
    unsigned acc = 0;
    for (size_t i = (size_t)blockIdx.x * 256 + threadIdx.x; i < n;
         i += (size_t)gridDim.x * 256) {
        uint4 v = m[i];
        acc |= v.x | v.y | v.z | v.w;
    }
    if (acc) atomicOr(&flags[1], 1u);
}

// ---------------------------------------------------------------------------
// fused 3-tensor fp32->bf16 convert (runs iff flags[0]==1); blockIdx.y picks
// ---------------------------------------------------------------------------
__global__ __launch_bounds__(256) void cvt3_f32_bf16(
    const float4* __restrict__ s0, us4* __restrict__ d0,
    const float4* __restrict__ s1, us4* __restrict__ d1,
    const float4* __restrict__ s2, us4* __restrict__ d2,
    unsigned n4, const unsigned* __restrict__ flags)
{
    if (flags[0] != 1u) return;
    const float4* s = (blockIdx.y == 0) ? s0 : (blockIdx.y == 1) ? s1 : s2;
    us4* d = (blockIdx.y == 0) ? d0 : (blockIdx.y == 1) ? d1 : d2;
    for (unsigned i = blockIdx.x * 256u + threadIdx.x; i < n4;
         i += gridDim.x * 256u) {
        float4 v = s[i];
        us4 o;
        o.x = f2bf(v.x); o.y = f2bf(v.y); o.z = f2bf(v.z); o.w = f2bf(v.w);
        d[i] = o;
    }
}

// fused 3-tensor bf16 copy (runs iff flags[0]==0)
__global__ __launch_bounds__(256) void copy3_bf16(
    const uint4* __restrict__ s0, uint4* __restrict__ d0,
    const uint4* __restrict__ s1, uint4* __restrict__ d1,
    const uint4* __restrict__ s2, uint4* __restrict__ d2,
    unsigned n16, const unsigned* __restrict__ flags)
{
    if (flags[0] != 0u) return;
    const uint4* s = (blockIdx.y == 0) ? s0 : (blockIdx.y == 1) ? s1 : s2;
    uint4* d = (blockIdx.y == 0) ? d0 : (blockIdx.y == 1) ? d1 : d2;
    for (unsigned i = blockIdx.x * 256u + threadIdx.x; i < n16;
         i += gridDim.x * 256u)
        d[i] = s[i];
}

// single-tensor fp32->bf16 (for seq_mask; fp32 path only)
__global__ __launch_bounds__(256) void cvt_f32_bf16(
    const float4* __restrict__ src, us4* __restrict__ dst, unsigned n4,
    const unsigned* __restrict__ flags)
{
    if (flags[0] != 1u) return;
    for (unsigned i = blockIdx.x * 256u + threadIdx.x; i < n4;
         i += gridDim.x * 256u) {
        float4 v = src[i];
        us4 o;
        o.x = f2bf(v.x); o.y = f2bf(v.y); o.z = f2bf(v.z); o.w = f2bf(v.w);
        dst[i] = o;
    }
}

// ---------------------------------------------------------------------------
// Weight transpose to bf16: dst[n][k] = (bf16)src[k][n], 1024x1024
// ---------------------------------------------------------------------------
template <typename T>
__global__ __launch_bounds__(256) void transpose_w(
    const T* __restrict__ src, unsigned short* __restrict__ dst,
    const unsigned* __restrict__ flag, unsigned want)
{
    if (*flag != want) return;
    __shared__ unsigned short tile[32][33];
    const int c0 = blockIdx.x * 32, r0 = blockIdx.y * 32;
    const int tx = threadIdx.x, ty = threadIdx.y;  // block (32,8)
#pragma unroll
    for (int i = 0; i < 32; i += 8)
        tile[ty + i][tx] = f2bf(ldf(src, (size_t)(r0 + ty + i) * 1024 + c0 + tx));
    __syncthreads();
#pragma unroll
    for (int i = 0; i < 32; i += 8)
        dst[(size_t)(c0 + ty + i) * 1024 + r0 + tx] = tile[tx][ty + i];
}

// fused 3-weight transpose; blockIdx.z picks tensor
template <typename T>
__global__ __launch_bounds__(256) void transpose_w3(
    const T* __restrict__ s0, const T* __restrict__ s1, const T* __restrict__ s2,
    unsigned short* __restrict__ d0, unsigned short* __restrict__ d1,
    unsigned short* __restrict__ d2,
    const unsigned* __restrict__ flag, unsigned want)
{
    if (*flag != want) return;
    const T* src = (blockIdx.z == 0) ? s0 : (blockIdx.z == 1) ? s1 : s2;
    unsigned short* dst = (blockIdx.z == 0) ? d0 : (blockIdx.z == 1) ? d1 : d2;
    __shared__ unsigned short tile[32][33];
    const int c0 = blockIdx.x * 32, r0 = blockIdx.y * 32;
    const int tx = threadIdx.x, ty = threadIdx.y;  // block (32,8)
#pragma unroll
    for (int i = 0; i < 32; i += 8)
        tile[ty + i][tx] = f2bf(ldf(src, (size_t)(r0 + ty + i) * 1024 + c0 + tx));
    __syncthreads();
#pragma unroll
    for (int i = 0; i < 32; i += 8)
        dst[(size_t)(c0 + ty + i) * 1024 + r0 + tx] = tile[tx][ty + i];
}

// ---------------------------------------------------------------------------
// GEMM: C[M=4096,N=1024] = A[4096,1024] @ Bt[1024,1024]^T  (A always bf16)
// 64x64 tile, 4 waves. Register-prefetch of the next K-tile (issue after the
// barrier, consume next iteration) hides global latency under MFMA.
// want==2 -> always run; else gated on flags[0]==want (output dtype).
// mode 0: row-major store; 1: head-split; 2: transposed head-split (V)
// ---------------------------------------------------------------------------
template <typename TO>
__global__ __launch_bounds__(256) void gemm_kernel(
    const unsigned short* __restrict__ A, const unsigned short* __restrict__ Bt,
    TO* __restrict__ out, int mode, const unsigned* __restrict__ flags, unsigned want)
{
    if (want != 2u && flags[0] != want) return;
    const int K = 1024;
    __shared__ __align__(16) unsigned short lA[64 * 72];
    __shared__ __align__(16) unsigned short lB[64 * 72];

    const int m0 = blockIdx.y * 64, n0 = blockIdx.x * 64;
    const int t = threadIdx.x;
    const int w = t >> 6, l = t & 63, quad = l >> 4, l15 = l & 15;
    const int srow = t >> 2, scol = (t & 3) * 16;

    const unsigned short* Arow = A + (size_t)(m0 + srow) * K + scol;
    const unsigned short* Brow = Bt + (size_t)(n0 + srow) * K + scol;

    f32x4 acc[4] = {};

    // prologue: load K-tile 0 into registers
    uint4 a0 = *(const uint4*)(Arow);
    uint4 a1 = *(const uint4*)(Arow + 8);
    uint4 b0 = *(const uint4*)(Brow);
    uint4 b1 = *(const uint4*)(Brow + 8);

    for (int k0 = 0; k0 < K; k0 += 64) {
        *(uint4*)&lA[srow * 72 + scol] = a0;
        *(uint4*)&lA[srow * 72 + scol + 8] = a1;
        *(uint4*)&lB[srow * 72 + scol] = b0;
        *(uint4*)&lB[srow * 72 + scol + 8] = b1;
        __syncthreads();
        // issue next-tile loads (wrap to 0 on last iter; harmless L2 hit)
        const int kn = (k0 + 64) & (K - 1);
        a0 = *(const uint4*)(Arow + kn);
        a1 = *(const uint4*)(Arow + kn + 8);
        b0 = *(const uint4*)(Brow + kn);
        b1 = *(const uint4*)(Brow + kn + 8);
#pragma unroll
        for (int kk = 0; kk < 64; kk += 32) {
            s16x8 af = *(const s16x8*)&lA[(w * 16 + l15) * 72 + kk + quad * 8];
#pragma unroll
            for (int g = 0; g < 4; g++) {
                s16x8 bf = *(const s16x8*)&lB[(g * 16 + l15) * 72 + kk + quad * 8];
                acc[g] = __builtin_amdgcn_mfma_f32_16x16x32_bf16(af, bf, acc[g], 0, 0, 0);
            }
        }
        __syncthreads();
    }

#pragma unroll
    for (int g = 0; g < 4; g++) {
#pragma unroll
        for (int r = 0; r < 4; r++) {
            int row = m0 + w * 16 + quad * 4 + r;
            int col = n0 + g * 16 + l15;
            float val = acc[g][r];
            if (mode == 0) {
                stf(out, (size_t)row * 1024 + col, val);
            } else {
                int b = row >> 11, s = row & 2047;
                int h = col >> 6, d = col & 63;
                if (mode == 1)
                    stf(out, (((size_t)(b * 16 + h) * 2048) + s) * 64 + d, val);
                else
                    stf(out, (((size_t)(b * 16 + h) * 64) + d) * 2048 + s, val);
            }
        }
    }
}

// ---------------------------------------------------------------------------
// Flash attention, post-softmax multiplicative seq_mask (bf16 smask always).
// Round-2 proven structure (branchless, straight-line softmax, VGPR<=64) +
// exp2-domain scores, deferred l-reduction, cvt_pk bf16 stores.
// ---------------------------------------------------------------------------
template <typename TM>
__global__ __launch_bounds__(256) void attn_kernel(
    const unsigned short* __restrict__ qh, const unsigned short* __restrict__ kh,
    const unsigned short* __restrict__ vt, const TM* __restrict__ amask,
    const unsigned short* __restrict__ smask, unsigned short* __restrict__ aout,
    const unsigned* __restrict__ flags, unsigned want)
{
    if (flags[0] != want) return;
    const bool useA = (flags[1] != 0u);
    const int S = 2048, DK = 64, H = 16;
    const int qt = blockIdx.x, h = blockIdx.y, b = blockIdx.z;
    const unsigned short* qhb = qh + (size_t)(b * H + h) * S * DK;
    const unsigned short* khb = kh + (size_t)(b * H + h) * S * DK;
    const unsigned short* vtb = vt + (size_t)(b * H + h) * DK * S;
    const TM* amb = amask + (size_t)b * S * S;
    const unsigned short* smb = smask + (size_t)b * S * S;

    __shared__ __align__(16) unsigned short lK[64 * 72];
    __shared__ __align__(16) unsigned short lV[64 * 72];
    __shared__ __align__(16) unsigned short lP[4][16 * 72];

    const int t = threadIdx.x;
    const int w = t >> 6, l = t & 63, quad = l >> 4, l15 = l & 15;
    const int q0 = qt * 64;
    const int srow = t >> 2, scol = (t & 3) * 16;

    const float SCALE2 = 0.18033688011112042f;  // 0.125 * log2(e)
    const float LOG2E  = 1.4426950408889634f;

    const int qrow_a = q0 + w * 16 + l15;
    s16x8 qf0 = *(const s16x8*)&qhb[(size_t)qrow_a * DK + quad * 8];
    s16x8 qf1 = *(const s16x8*)&qhb[(size_t)qrow_a * DK + 32 + quad * 8];

    float mrun[4], lsum[4];
    f32x4 o[4] = {};
#pragma unroll
    for (int r = 0; r < 4; r++) { mrun[r] = -INFINITY; lsum[r] = 0.0f; }

    for (int k0 = 0; k0 < S; k0 += 64) {
        const uint4* gk = (const uint4*)&khb[(size_t)(k0 + srow) * DK + scol];
        const uint4* gv = (const uint4*)&vtb[(size_t)srow * S + k0 + scol];
        uint4 ka = gk[0], kb = gk[1];
        uint4 va = gv[0], vb = gv[1];
        *(uint4*)&lK[srow * 72 + scol] = ka;
        *(uint4*)&lK[srow * 72 + scol + 8] = kb;
        *(uint4*)&lV[srow * 72 + scol] = va;
        *(uint4*)&lV[srow * 72 + scol + 8] = vb;
        __syncthreads();

        f32x4 sc[4] = {};
#pragma unroll
        for (int kk = 0; kk < 64; kk += 32) {
            s16x8 af = (kk == 0) ? qf0 : qf1;
#pragma unroll
            for (int g = 0; g < 4; g++) {
                s16x8 bf = *(const s16x8*)&lK[(g * 16 + l15) * 72 + kk + quad * 8];
                sc[g] = __builtin_amdgcn_mfma_f32_16x16x32_bf16(af, bf, sc[g], 0, 0, 0);
            }
        }

        if (!useA) {
            // hot path: no additive mask. Branchless straight-line softmax.
#pragma unroll
            for (int r = 0; r < 4; r++) {
                const int qr = q0 + w * 16 + quad * 4 + r;
                const size_t mrow = (size_t)qr * S + k0;
                float sv0 = sc[0][r] * SCALE2;
                float sv1 = sc[1][r] * SCALE2;
                float sv2 = sc[2][r] * SCALE2;
                float sv3 = sc[3][r] * SCALE2;
                float mx = fmaxf(fmaxf(sv0, sv1), fmaxf(sv2, sv3));
#pragma unroll
                for (int d = 1; d < 16; d <<= 1) mx = fmaxf(mx, __shfl_xor(mx, d));
                float mnew = fmaxf(mrun[r], mx);
                float alpha = EXP2F(mrun[r] - mnew);  // exp2(-inf)=0 first tile
                float e0 = EXP2F(sv0 - mnew);
                float e1 = EXP2F(sv1 - mnew);
                float e2 = EXP2F(sv2 - mnew);
                float e3 = EXP2F(sv3 - mnew);
                lsum[r] = lsum[r] * alpha + ((e0 + e1) + (e2 + e3));
                mrun[r] = mnew;
#pragma unroll
                for (int g = 0; g < 4; g++) o[g][r] *= alpha;
                const int rowp = (quad * 4 + r) * 72;
                lP[w][rowp + 0 * 16 + l15] = f2bf_fast(e0 * bf2f(smb[mrow + 0 * 16 + l15]));
                lP[w][rowp + 1 * 16 + l15] = f2bf_fast(e1 * bf2f(smb[mrow + 1 * 16 + l15]));
                lP[w][rowp + 2 * 16 + l15] = f2bf_fast(e2 * bf2f(smb[mrow + 2 * 16 + l15]));
                lP[w][rowp + 3 * 16 + l15] = f2bf_fast(e3 * bf2f(smb[mrow + 3 * 16 + l15]));
            }
        } else {
            // cold path: additive att_mask present.
#pragma unroll
            for (int r = 0; r < 4; r++) {
                const int qr = q0 + w * 16 + quad * 4 + r;
                const size_t mrow = (size_t)qr * S + k0;
                float sv0 = fmaf((float)ldf(amb, mrow + 0 * 16 + l15), LOG2E, sc[0][r] * SCALE2);
                float sv1 = fmaf((float)ldf(amb, mrow + 1 * 16 + l15), LOG2E, sc[1][r] * SCALE2);
                float sv2 = fmaf((float)ldf(amb, mrow + 2 * 16 + l15), LOG2E, sc[2][r] * SCALE2);
                float sv3 = fmaf((float)ldf(amb, mrow + 3 * 16 + l15), LOG2E, sc[3][r] * SCALE2);
                float mx = fmaxf(fmaxf(sv0, sv1), fmaxf(sv2, sv3));
#pragma unroll
                for (int d = 1; d < 16; d <<= 1) mx = fmaxf(mx, __shfl_xor(mx, d));
                float mnew = fmaxf(mrun[r], mx);
                float alpha = EXP2F(mrun[r] - mnew);
                float e0 = EXP2F(sv0 - mnew);
                float e1 = EXP2F(sv1 - mnew);
                float e2 = EXP2F(sv2 - mnew);
                float e3 = EXP2F(sv3 - mnew);
                lsum[r] = lsum[r] * alpha + ((e0 + e1) + (e2 + e3));
                mrun[r] = mnew;
#pragma unroll
                for (int g = 0; g < 4; g++) o[g][r] *= alpha;
                const int rowp = (quad * 4 + r) * 72;
                lP[w][rowp + 0 * 16 + l15] = f2bf_fast(e0 * bf2f(smb[mrow + 0 * 16 + l15]));
                lP[w][rowp + 1 * 16 + l15] = f2bf_fast(e1 * bf2f(smb[mrow + 1 * 16 + l15]));
                lP[w][rowp + 2 * 16 + l15] = f2bf_fast(e2 * bf2f(smb[mrow + 2 * 16 + l15]));
                lP[w][rowp + 3 * 16 + l15] = f2bf_fast(e3 * bf2f(smb[mrow + 3 * 16 + l15]));
            }
        }
        __syncthreads();

#pragma unroll
        for (int kk = 0; kk < 64; kk += 32) {
            s16x8 pf = *(const s16x8*)&lP[w][l15 * 72 + kk + quad * 8];
#pragma unroll
            for (int g = 0; g < 4; g++) {
                s16x8 vf = *(const s16x8*)&lV[(g * 16 + l15) * 72 + kk + quad * 8];
                o[g] = __builtin_amdgcn_mfma_f32_16x16x32_bf16(pf, vf, o[g], 0, 0, 0);
            }
        }
        __syncthreads();
    }

#pragma unroll
    for (int r = 0; r < 4; r++) {
        float ls = lsum[r];
#pragma unroll
        for (int d = 1; d < 16; d <<= 1) ls += __shfl_xor(ls, d);
        float inv = 1.0f / ls;
        const int qr = q0 + w * 16 + quad * 4 + r;
#pragma unroll
        for (int g = 0; g < 4; g++) {
            aout[((size_t)(b * S + qr)) * 1024 + h * 64 + g * 16 + l15] =
                f2bf_fast(o[g][r] * inv);
        }
    }
}

// ---------------------------------------------------------------------------
extern "C" void kernel_launch(void* const* d_in, const int* in_sizes, int n_in,
                              void* d_out, int out_size, void* d_ws, size_t ws_size,
                              hipStream_t stream)
{
    // setup_inputs order: q, v, k, att_mask, seq_mask, Wq, Wk, Wv, Wo
    const void* q   = d_in[0];
    const void* v   = d_in[1];
    const void* k   = d_in[2];
    const void* att = d_in[3];
    const void* seq = d_in[4];
    const void* Wq  = d_in[5];
    const void* Wk  = d_in[6];
    const void* Wv  = d_in[7];
    const void* Wo  = d_in[8];

    const size_t WELEM = 1024 * 1024;
    const size_t HELEM = (size_t)2 * 16 * 2048 * 64;  // 4,194,304 elements

    unsigned* flags = (unsigned*)d_ws;
    unsigned short* base = (unsigned short*)((char*)d_ws + 512);
    unsigned short* r0 = base;           // 8MB: Wq^T,Wk^T,Wv^T ; later ao
    unsigned short* qh = base + HELEM;   // 8MB: qh ; later Wo^T
    unsigned short* kh = qh + HELEM;     // 8MB
    unsigned short* vt = kh + HELEM;     // 8MB
    unsigned short* qb = vt + HELEM;     // 8MB bf16(q)
    unsigned short* kb = qb + HELEM;     // 8MB bf16(k)
    unsigned short* vb = kb + HELEM;     // 8MB bf16(v)
    unsigned short* seqb = qb;           // 16MB bf16(seq_mask), overlaps qb+kb
                                         //  (written AFTER projections finish)
    // total ws: 512 + 7*8MB = 56.5 MB

    const dim3 tg(32, 32), tb(32, 8);
    const dim3 tg3(32, 32, 3);
    const dim3 gg(16, 64), gb(256);
    const dim3 ag(32, 16, 2), ab(256);

    probe_dtype<<<1, 256, 0, stream>>>((const unsigned short*)q, flags);
    probe_zero<<<1024, 256, 0, stream>>>((const uint4*)att, flags);

    // ---- bulk convert/copy q,k,v to bf16 (one of the pair no-ops) ----
    const unsigned n4h = 1048576u, n16h = 524288u;   // HELEM/4, HELEM/8
    cvt3_f32_bf16<<<dim3(512, 3), 256, 0, stream>>>(
        (const float4*)q, (us4*)qb, (const float4*)k, (us4*)kb,
        (const float4*)v, (us4*)vb, n4h, flags);
    copy3_bf16<<<dim3(512, 3), 256, 0, stream>>>(
        (const uint4*)q, (uint4*)qb, (const uint4*)k, (uint4*)kb,
        (const uint4*)v, (uint4*)vb, n16h, flags);

    // ---- transposes of Wq, Wk, Wv (one dtype variant no-ops) ----
    transpose_w3<unsigned short><<<tg3, tb, 0, stream>>>(
        (const unsigned short*)Wq, (const unsigned short*)Wk, (const unsigned short*)Wv,
        r0 + 0 * WELEM, r0 + 1 * WELEM, r0 + 2 * WELEM, flags, 0);
    transpose_w3<float><<<tg3, tb, 0, stream>>>(
        (const float*)Wq, (const float*)Wk, (const float*)Wv,
        r0 + 0 * WELEM, r0 + 1 * WELEM, r0 + 2 * WELEM, flags, 1);

    // ---- projections (always run; A is bf16) ----
    gemm_kernel<unsigned short><<<gg, gb, 0, stream>>>(qb, r0 + 0 * WELEM, qh, 1, flags, 2);
    gemm_kernel<unsigned short><<<gg, gb, 0, stream>>>(kb, r0 + 1 * WELEM, kh, 1, flags, 2);
    gemm_kernel<unsigned short><<<gg, gb, 0, stream>>>(vb, r0 + 2 * WELEM, vt, 2, flags, 2);

    // ---- seq_mask -> bf16 (fp32 path only; bf16 path reads seq directly) ----
    const unsigned n4s = 2097152u;  // 8,388,608 elems / 4
    cvt_f32_bf16<<<2048, 256, 0, stream>>>((const float4*)seq, (us4*)seqb, n4s, flags);

    // ---- attention (ao overwrites r0; weights no longer needed) ----
    unsigned short* ao = r0;
    attn_kernel<unsigned short><<<ag, ab, 0, stream>>>(
        qh, kh, vt, (const unsigned short*)att, (const unsigned short*)seq, ao, flags, 0);
    attn_kernel<float><<<ag, ab, 0, stream>>>(
        qh, kh, vt, (const float*)att, seqb, ao, flags, 1);

    // ---- Wo transpose into qh region (qh no longer needed) ----
    transpose_w<unsigned short><<<tg, tb, 0, stream>>>((const unsigned short*)Wo, qh, flags, 0);
    transpose_w<float><<<tg, tb, 0, stream>>>((const float*)Wo, qh, flags, 1);

    // ---- output projection ----
    gemm_kernel<unsigned short><<<gg, gb, 0, stream>>>(ao, qh, (unsigned short*)d_out, 0, flags, 0);
    gemm_kernel<float><<<gg, gb, 0, stream>>>(ao, qh, (float*)d_out, 0, flags, 1);
}